// Round 7
// baseline (31248.987 us; speedup 1.0000x reference)
//
#include <hip/hip_runtime.h>
#include <stdint.h>

// GRU encoder: VOCAB=50257, EMBED=HIDDEN=1024, SEQ=4096.
// Phase 1: x-projections, output TRANSPOSED [row][t] (round-7: per-step x
//          reads become L1-hot instead of one fresh HBM line per 8B).
// Phase 2: 4096-step scan, 64 WGs x 512 threads, fused (tag|value) cells.
//          ROUND-7 exchange: sentinel-counter + one-shot gather. Producers
//          RMW their cells, drain vmcnt, fetch_add a per-WG sentinel (64B
//          stride, own line). Only wave0 polls sentinels (64 req/line on 64
//          lines); data lines get ONE tag-verified burst per exchange instead
//          of a sustained 256-requester poll storm that queues the publish.

#define HID    1024
#define SEQLEN 4096
#define NWG    64
#define RPW    16      // hidden rows per WG
#define BLOCK  512     // 8 waves; wave w owns rows 16g+2w, 16g+2w+1
#define SSTR   8       // sentinel stride in u64 (64B = one line per WG)

typedef unsigned long long u64;

// ---------------------------------------------------------------------------
// Phase 1: CT[i][t] = sum_e emb[seq[t],e] * W[i,e]   (transposed output)
// ---------------------------------------------------------------------------
__global__ __launch_bounds__(256) void proj_gemm(
    const int* __restrict__ seq, const float* __restrict__ emb,
    const float* __restrict__ Wrx, const float* __restrict__ Wzx,
    const float* __restrict__ Wx,
    float* __restrict__ xrT, float* __restrict__ xzT, float* __restrict__ xhT)
{
  __shared__ float As[32][68];   // [k][t]
  __shared__ float Bs[32][68];   // [k][i]
  __shared__ int   idx[64];

  const float* W = (blockIdx.z == 0) ? Wrx : (blockIdx.z == 1) ? Wzx : Wx;
  float*       C = (blockIdx.z == 0) ? xrT : (blockIdx.z == 1) ? xzT : xhT;

  const int tid = threadIdx.x;
  const int t0 = blockIdx.y * 64;
  const int i0 = blockIdx.x * 64;
  if (tid < 64) idx[tid] = seq[t0 + tid];
  __syncthreads();

  float acc[4][4] = {};                     // acc[i][j]: i-dim x t-dim
  const int tx = tid & 15, ty = tid >> 4;
  const int c4 = (tid & 7) * 4;
  const int r8 = tid >> 3;

  for (int k0 = 0; k0 < HID; k0 += 32) {
    for (int l = 0; l < 2; ++l) {
      const int rr = r8 + l * 32;
      float4 av = *(const float4*)(emb + (size_t)idx[rr] * HID + k0 + c4);
      As[c4+0][rr]=av.x; As[c4+1][rr]=av.y; As[c4+2][rr]=av.z; As[c4+3][rr]=av.w;
      float4 bv = *(const float4*)(W + (size_t)(i0 + rr) * HID + k0 + c4);
      Bs[c4+0][rr]=bv.x; Bs[c4+1][rr]=bv.y; Bs[c4+2][rr]=bv.z; Bs[c4+3][rr]=bv.w;
    }
    __syncthreads();
    #pragma unroll
    for (int k = 0; k < 32; ++k) {
      float a[4], b[4];
      *(float4*)a = *(const float4*)&Bs[k][ty * 4];   // i-dim (rows of CT)
      *(float4*)b = *(const float4*)&As[k][tx * 4];   // t-dim (cols of CT)
      #pragma unroll
      for (int i = 0; i < 4; ++i)
        #pragma unroll
        for (int j = 0; j < 4; ++j)
          acc[i][j] = fmaf(a[i], b[j], acc[i][j]);
    }
    __syncthreads();
  }
  // CT[i][t]: coalesced float4 along t.
  #pragma unroll
  for (int i = 0; i < 4; ++i) {
    float4 v = make_float4(acc[i][0], acc[i][1], acc[i][2], acc[i][3]);
    *(float4*)(C + (size_t)(i0 + ty * 4 + i) * SEQLEN + t0 + tx * 4) = v;
  }
}

// ---------------------------------------------------------------------------
// Fused-cell primitives. Cell = u64 {low: f32 bits, high: step tag}.
// ---------------------------------------------------------------------------
__device__ __forceinline__ void publish2(u64* cells, int row, float a, float b,
                                         unsigned tag) {
  u64 ca = ((u64)tag << 32) | (u64)__float_as_uint(a);
  u64 cb = ((u64)tag << 32) | (u64)__float_as_uint(b);
  (void)__hip_atomic_exchange(&cells[row],     ca, __ATOMIC_RELAXED,
                              __HIP_MEMORY_SCOPE_AGENT);
  (void)__hip_atomic_exchange(&cells[row + 1], cb, __ATOMIC_RELAXED,
                              __HIP_MEMORY_SCOPE_AGENT);
}

// One-shot (expected) tag-verified 16B gather; loops only if a tag is stale.
__device__ __forceinline__ float2 gather_pair(const u64* cells, int pair,
                                              unsigned want, int* budget) {
  const float* p = (const float*)(cells + 2 * pair);
  float4 v;
  for (;;) {
    asm volatile("global_load_dwordx4 %0, %1, off sc0 sc1\n\ts_waitcnt vmcnt(0)"
                 : "=v"(v) : "v"(p) : "memory");
    if (__float_as_uint(v.y) == want && __float_as_uint(v.w) == want) break;
    if (--(*budget) <= 0) break;
  }
  return make_float2(v.x, v.z);
}

// Wave0-only: lane g polls WG g's sentinel counter until all 64 reach `need`.
__device__ __forceinline__ void poll_sent(const u64* s, int lane, u64 need,
                                          int* budget) {
  const u64* p = s + (size_t)lane * SSTR;
  for (;;) {
    u64 v = __hip_atomic_load((u64*)p, __ATOMIC_RELAXED, __HIP_MEMORY_SCOPE_AGENT);
    if (__all(v >= need)) break;
    if (--(*budget) <= 0) break;
  }
}

// ---------------------------------------------------------------------------
// Phase 2: persistent scan. WG g owns rows [16g,16g+16); wave w (of 8) owns
// rows 16g+2w, +1; lane l covers h-columns {q*256+4l+j} (q-strided,
// conflict-free LDS). Per exchange: waves publish rows (RMW), lane0 drains
// vmcnt then fetch_adds sent[g] (+1 per wave => 8 per step); wave0 polls all
// 64 sentinels; barrier; all threads one-shot gather + LDS; barrier.
// ---------------------------------------------------------------------------
__global__ __launch_bounds__(BLOCK, 2) void rnn_scan(
    const float* __restrict__ Wzh, const float* __restrict__ Wrh,
    const float* __restrict__ Whh,
    const float* __restrict__ xzT, const float* __restrict__ xrT,
    const float* __restrict__ xhT,
    u64* __restrict__ hcell,     // [2][HID]
    u64* __restrict__ rhcell,    // [2][HID]
    u64* __restrict__ sent_h,    // [NWG*SSTR] cumulative wave-publish counter
    u64* __restrict__ sent_rh,   // [NWG*SSTR]
    float* __restrict__ out)
{
  const int tid  = threadIdx.x;
  const int wave = tid >> 6, lane = tid & 63;
  const int g    = blockIdx.x;
  const int rowA = g * RPW + wave * 2;

  __shared__ float h_lds[HID];
  __shared__ float rh_lds[HID];

  // Weights: wgt[m][rr][q*4+j] = Wm[rowA+rr][q*256 + 4*lane + j].
  float wgt[3][2][16];
  #pragma unroll
  for (int m = 0; m < 3; ++m) {
    const float* Wm = (m == 0) ? Wzh : (m == 1) ? Wrh : Whh;
    #pragma unroll
    for (int rr = 0; rr < 2; ++rr) {
      const float* p = Wm + (size_t)(rowA + rr) * HID + lane * 4;
      #pragma unroll
      for (int q = 0; q < 4; ++q) {
        float4 v = *(const float4*)(p + q * 256);
        wgt[m][rr][q*4+0] = v.x; wgt[m][rr][q*4+1] = v.y;
        wgt[m][rr][q*4+2] = v.z; wgt[m][rr][q*4+3] = v.w;
      }
    }
  }

  int budget = 1 << 21;
  float xzv[2], xrv[2], xhv[2], zv[2], hprev[2];

  for (int t = 1; t <= SEQLEN; ++t) {
    // x rows for this step: [row][t] layout -> L1-hot scalar loads.
    if (lane == 0) {
      #pragma unroll
      for (int rr = 0; rr < 2; ++rr) {
        xzv[rr] = xzT[(size_t)(rowA + rr) * SEQLEN + (t - 1)];
        xrv[rr] = xrT[(size_t)(rowA + rr) * SEQLEN + (t - 1)];
        xhv[rr] = xhT[(size_t)(rowA + rr) * SEQLEN + (t - 1)];
      }
    }

    // ---- exchange 1: h_{t-1} (tag t-1, parity (t-1)&1) ----
    float2 hv;
    if (t == 1) {
      hv = make_float2(0.f, 0.f);
    } else {
      if (wave == 0) poll_sent(sent_h, lane, 8ull * (u64)(t - 1), &budget);
      __syncthreads();                               // sentinel verdict
      hv = gather_pair(hcell + ((t - 1) & 1) * HID, tid,
                       (unsigned)(t - 1), &budget);
    }
    *(float2*)&h_lds[2 * tid] = hv;
    __syncthreads();                                 // [B1]

    // gate dots over q-strided 16 columns, 64-lane shuffle reduce.
    float hr[16];
    #pragma unroll
    for (int q = 0; q < 4; ++q)
      *(float4*)&hr[q*4] = *(const float4*)&h_lds[q * 256 + lane * 4];
    float az[2] = {0.f, 0.f}, ar[2] = {0.f, 0.f};
    #pragma unroll
    for (int rr = 0; rr < 2; ++rr)
      #pragma unroll
      for (int c = 0; c < 16; ++c) {
        az[rr] = fmaf(wgt[0][rr][c], hr[c], az[rr]);
        ar[rr] = fmaf(wgt[1][rr][c], hr[c], ar[rr]);
      }
    #pragma unroll
    for (int m = 1; m < 64; m <<= 1) {
      az[0] += __shfl_xor(az[0], m, 64);
      az[1] += __shfl_xor(az[1], m, 64);
      ar[0] += __shfl_xor(ar[0], m, 64);
      ar[1] += __shfl_xor(ar[1], m, 64);
    }
    if (lane == 0) {
      float rh[2];
      #pragma unroll
      for (int rr = 0; rr < 2; ++rr) {
        hprev[rr] = h_lds[rowA + rr];
        zv[rr]    = 1.f / (1.f + __expf(-(xzv[rr] + az[rr])));
        float rg  = 1.f / (1.f + __expf(-(xrv[rr] + ar[rr])));
        rh[rr]    = rg * hprev[rr];
      }
      publish2(rhcell + (t & 1) * HID, rowA, rh[0], rh[1], (unsigned)t);
      asm volatile("s_waitcnt vmcnt(0)" ::: "memory");   // cells at MALL
      (void)__hip_atomic_fetch_add(&sent_rh[(size_t)g * SSTR], 1ull,
                                   __ATOMIC_RELAXED, __HIP_MEMORY_SCOPE_AGENT);
    }

    // ---- exchange 2: (r*h)_t (tag t, parity t&1) ----
    if (wave == 0) poll_sent(sent_rh, lane, 8ull * (u64)t, &budget);
    __syncthreads();                                 // sentinel verdict
    {
      float2 rv = gather_pair(rhcell + (t & 1) * HID, tid, (unsigned)t, &budget);
      *(float2*)&rh_lds[2 * tid] = rv;
    }
    __syncthreads();                                 // [B2]

    float rr16[16];
    #pragma unroll
    for (int q = 0; q < 4; ++q)
      *(float4*)&rr16[q*4] = *(const float4*)&rh_lds[q * 256 + lane * 4];
    float ac[2] = {0.f, 0.f};
    #pragma unroll
    for (int rr = 0; rr < 2; ++rr)
      #pragma unroll
      for (int c = 0; c < 16; ++c)
        ac[rr] = fmaf(wgt[2][rr][c], rr16[c], ac[rr]);
    #pragma unroll
    for (int m = 1; m < 64; m <<= 1) {
      ac[0] += __shfl_xor(ac[0], m, 64);
      ac[1] += __shfl_xor(ac[1], m, 64);
    }
    if (lane == 0) {
      float hn[2];
      #pragma unroll
      for (int rr = 0; rr < 2; ++rr) {
        float cand = tanhf(xhv[rr] + ac[rr]);
        hn[rr]     = zv[rr] * hprev[rr] + (1.f - zv[rr]) * cand;
      }
      publish2(hcell + (t & 1) * HID, rowA, hn[0], hn[1], (unsigned)t);
      asm volatile("s_waitcnt vmcnt(0)" ::: "memory");
      (void)__hip_atomic_fetch_add(&sent_h[(size_t)g * SSTR], 1ull,
                                   __ATOMIC_RELAXED, __HIP_MEMORY_SCOPE_AGENT);
      if (t == SEQLEN) { out[rowA] = hn[0]; out[rowA + 1] = hn[1]; }
    }
  }
}

// ---------------------------------------------------------------------------
extern "C" void kernel_launch(void* const* d_in, const int* in_sizes, int n_in,
                              void* d_out, int out_size, void* d_ws, size_t ws_size,
                              hipStream_t stream) {
  (void)in_sizes; (void)n_in; (void)out_size; (void)ws_size;

  const int*   seq = (const int*)d_in[0];
  const float* emb = (const float*)d_in[1];
  const float* Wrx = (const float*)d_in[2];
  const float* Wrh = (const float*)d_in[3];
  const float* Wzx = (const float*)d_in[4];
  const float* Wzh = (const float*)d_in[5];
  const float* Wx  = (const float*)d_in[6];
  const float* Wh  = (const float*)d_in[7];

  char* ws = (char*)d_ws;
  const size_t PROJ = (size_t)SEQLEN * HID * sizeof(float);   // 16 MB each
  float* xrT    = (float*)(ws);
  float* xzT    = (float*)(ws + PROJ);
  float* xhT    = (float*)(ws + 2 * PROJ);
  u64*   hcell  = (u64*)(ws + 3 * PROJ);                      // [2][HID]
  u64*   rhcell = hcell + 2 * HID;                            // [2][HID]
  u64*   sent_h = rhcell + 2 * HID;                           // [NWG*SSTR]
  u64*   sent_rh= sent_h + NWG * SSTR;                        // [NWG*SSTR]

  // Per-launch reset (replay-safe): cell tags to 0xFF (never matches 1..4096),
  // sentinel counters to 0.
  (void)hipMemsetAsync(hcell, 0xFF, 4 * HID * sizeof(u64), stream);
  (void)hipMemsetAsync(sent_h, 0x00, 2 * NWG * SSTR * sizeof(u64), stream);

  proj_gemm<<<dim3(HID / 64, SEQLEN / 64, 3), 256, 0, stream>>>(
      seq, emb, Wrx, Wzx, Wx, xrT, xzT, xhT);

  rnn_scan<<<dim3(NWG), BLOCK, 0, stream>>>(
      Wzh, Wrh, Wh, xzT, xrT, xhT, hcell, rhcell, sent_h, sent_rh,
      (float*)d_out);
}

// Round 8
// 29701.074 us; speedup vs baseline: 1.0521x; 1.0521x over previous
//
#include <hip/hip_runtime.h>
#include <stdint.h>

// GRU encoder: VOCAB=50257, EMBED=HIDDEN=1024, SEQ=4096.
// Phase 1: x-projections, output transposed [row][t] (L1-hot per-step reads).
// Phase 2: 4096-step scan, 64 WGs x 512 threads, fused (tag|value) u64 cells,
//          RMW publish (R6). ROUND-8 CHANGE (single A/B vs R6): consumer
//          polls use compiler-generated AGENT-scope atomic u64 loads instead
//          of hand-asm `sc0 sc1` (= SYSTEM scope). Agent scope stops at the
//          MALL coherence point; system scope was punching every poll through
//          to the HBM path (signature: ~600 MB FETCH_SIZE from a 48 KB
//          working set).

#define HID    1024
#define SEQLEN 4096
#define NWG    64
#define RPW    16      // hidden rows per WG
#define BLOCK  512     // 8 waves; wave w owns rows 16g+2w, 16g+2w+1

typedef unsigned long long u64;

// ---------------------------------------------------------------------------
// Phase 1: CT[i][t] = sum_e emb[seq[t],e] * W[i,e]   (transposed output)
// ---------------------------------------------------------------------------
__global__ __launch_bounds__(256) void proj_gemm(
    const int* __restrict__ seq, const float* __restrict__ emb,
    const float* __restrict__ Wrx, const float* __restrict__ Wzx,
    const float* __restrict__ Wx,
    float* __restrict__ xrT, float* __restrict__ xzT, float* __restrict__ xhT)
{
  __shared__ float As[32][68];   // [k][t]
  __shared__ float Bs[32][68];   // [k][i]
  __shared__ int   idx[64];

  const float* W = (blockIdx.z == 0) ? Wrx : (blockIdx.z == 1) ? Wzx : Wx;
  float*       C = (blockIdx.z == 0) ? xrT : (blockIdx.z == 1) ? xzT : xhT;

  const int tid = threadIdx.x;
  const int t0 = blockIdx.y * 64;
  const int i0 = blockIdx.x * 64;
  if (tid < 64) idx[tid] = seq[t0 + tid];
  __syncthreads();

  float acc[4][4] = {};                     // acc[i][j]: i-dim x t-dim
  const int tx = tid & 15, ty = tid >> 4;
  const int c4 = (tid & 7) * 4;
  const int r8 = tid >> 3;

  for (int k0 = 0; k0 < HID; k0 += 32) {
    for (int l = 0; l < 2; ++l) {
      const int rr = r8 + l * 32;
      float4 av = *(const float4*)(emb + (size_t)idx[rr] * HID + k0 + c4);
      As[c4+0][rr]=av.x; As[c4+1][rr]=av.y; As[c4+2][rr]=av.z; As[c4+3][rr]=av.w;
      float4 bv = *(const float4*)(W + (size_t)(i0 + rr) * HID + k0 + c4);
      Bs[c4+0][rr]=bv.x; Bs[c4+1][rr]=bv.y; Bs[c4+2][rr]=bv.z; Bs[c4+3][rr]=bv.w;
    }
    __syncthreads();
    #pragma unroll
    for (int k = 0; k < 32; ++k) {
      float a[4], b[4];
      *(float4*)a = *(const float4*)&Bs[k][ty * 4];   // i-dim (rows of CT)
      *(float4*)b = *(const float4*)&As[k][tx * 4];   // t-dim (cols of CT)
      #pragma unroll
      for (int i = 0; i < 4; ++i)
        #pragma unroll
        for (int j = 0; j < 4; ++j)
          acc[i][j] = fmaf(a[i], b[j], acc[i][j]);
    }
    __syncthreads();
  }
  // CT[i][t]: coalesced float4 along t.
  #pragma unroll
  for (int i = 0; i < 4; ++i) {
    float4 v = make_float4(acc[i][0], acc[i][1], acc[i][2], acc[i][3]);
    *(float4*)(C + (size_t)(i0 + ty * 4 + i) * SEQLEN + t0 + tx * 4) = v;
  }
}

// ---------------------------------------------------------------------------
// Fused-cell primitives. Cell = u64 {low: f32 bits, high: step tag}.
// PUBLISH: agent-scope atomic exchange (RMW executes at the coherent point).
// CONSUME: two relaxed AGENT-scope atomic u64 loads (compiler emits the
// correct gfx950 cache-scope flags; independent loads co-issue, one wait).
// ---------------------------------------------------------------------------
__device__ __forceinline__ void publish2(u64* cells, int row, float a, float b,
                                         unsigned tag) {
  u64 ca = ((u64)tag << 32) | (u64)__float_as_uint(a);
  u64 cb = ((u64)tag << 32) | (u64)__float_as_uint(b);
  (void)__hip_atomic_exchange(&cells[row],     ca, __ATOMIC_RELAXED,
                              __HIP_MEMORY_SCOPE_AGENT);
  (void)__hip_atomic_exchange(&cells[row + 1], cb, __ATOMIC_RELAXED,
                              __HIP_MEMORY_SCOPE_AGENT);
}

// Poll this thread's 2 cells until both tags == want. Budget bail-out turns
// a pathological stall into an absmax fail instead of a hang.
__device__ __forceinline__ float2 poll_pair(const u64* cells, int pair,
                                            unsigned want, int* budget) {
  const u64* p = cells + 2 * pair;
  u64 c0, c1;
  for (;;) {
    c0 = __hip_atomic_load((u64*)(p + 0), __ATOMIC_RELAXED,
                           __HIP_MEMORY_SCOPE_AGENT);
    c1 = __hip_atomic_load((u64*)(p + 1), __ATOMIC_RELAXED,
                           __HIP_MEMORY_SCOPE_AGENT);
    if ((unsigned)(c0 >> 32) == want && (unsigned)(c1 >> 32) == want) break;
    if (--(*budget) <= 0) break;
  }
  return make_float2(__uint_as_float((unsigned)c0),
                     __uint_as_float((unsigned)c1));
}

// ---------------------------------------------------------------------------
// Phase 2: persistent scan. WG g owns rows [16g,16g+16); wave w (of 8) owns
// rows 16g+2w, +1; lane l covers h-columns {q*256+4l+j} (q-strided,
// conflict-free LDS). Consumer thread tid polls cells {2tid, 2tid+1}.
// Per step: poll h -> B1 -> gates -> publish r*h -> poll rh -> B2 ->
// candidate -> publish h. 2 visibility events, 2 barriers per step.
// ---------------------------------------------------------------------------
__global__ __launch_bounds__(BLOCK, 2) void rnn_scan(
    const float* __restrict__ Wzh, const float* __restrict__ Wrh,
    const float* __restrict__ Whh,
    const float* __restrict__ xzT, const float* __restrict__ xrT,
    const float* __restrict__ xhT,
    u64* __restrict__ hcell,     // [2][HID]
    u64* __restrict__ rhcell,    // [2][HID]
    float* __restrict__ out)
{
  const int tid  = threadIdx.x;
  const int wave = tid >> 6, lane = tid & 63;
  const int g    = blockIdx.x;
  const int rowA = g * RPW + wave * 2;

  __shared__ float h_lds[HID];
  __shared__ float rh_lds[HID];

  // Weights: wgt[m][rr][q*4+j] = Wm[rowA+rr][q*256 + 4*lane + j].
  float wgt[3][2][16];
  #pragma unroll
  for (int m = 0; m < 3; ++m) {
    const float* Wm = (m == 0) ? Wzh : (m == 1) ? Wrh : Whh;
    #pragma unroll
    for (int rr = 0; rr < 2; ++rr) {
      const float* p = Wm + (size_t)(rowA + rr) * HID + lane * 4;
      #pragma unroll
      for (int q = 0; q < 4; ++q) {
        float4 v = *(const float4*)(p + q * 256);
        wgt[m][rr][q*4+0] = v.x; wgt[m][rr][q*4+1] = v.y;
        wgt[m][rr][q*4+2] = v.z; wgt[m][rr][q*4+3] = v.w;
      }
    }
  }

  int budget = 1 << 21;
  float xzv[2], xrv[2], xhv[2], zv[2], hprev[2];

  for (int t = 1; t <= SEQLEN; ++t) {
    // ---- exchange 1: h_{t-1} (tag t-1, parity (t-1)&1) ----
    if (t == 1) {
      *(float2*)&h_lds[2 * tid] = make_float2(0.f, 0.f);
    } else {
      float2 hv = poll_pair(hcell + ((t - 1) & 1) * HID, tid,
                            (unsigned)(t - 1), &budget);
      *(float2*)&h_lds[2 * tid] = hv;
    }

    // x rows for this step ([row][t] layout -> L1-hot): hides under B1.
    if (lane == 0) {
      #pragma unroll
      for (int rr = 0; rr < 2; ++rr) {
        xzv[rr] = xzT[(size_t)(rowA + rr) * SEQLEN + (t - 1)];
        xrv[rr] = xrT[(size_t)(rowA + rr) * SEQLEN + (t - 1)];
        xhv[rr] = xhT[(size_t)(rowA + rr) * SEQLEN + (t - 1)];
      }
    }
    __syncthreads();                                   // [B1]

    // gate dots over q-strided 16 columns, 64-lane shuffle reduce.
    float hr[16];
    #pragma unroll
    for (int q = 0; q < 4; ++q)
      *(float4*)&hr[q*4] = *(const float4*)&h_lds[q * 256 + lane * 4];
    float az[2] = {0.f, 0.f}, ar[2] = {0.f, 0.f};
    #pragma unroll
    for (int rr = 0; rr < 2; ++rr)
      #pragma unroll
      for (int c = 0; c < 16; ++c) {
        az[rr] = fmaf(wgt[0][rr][c], hr[c], az[rr]);
        ar[rr] = fmaf(wgt[1][rr][c], hr[c], ar[rr]);
      }
    #pragma unroll
    for (int m = 1; m < 64; m <<= 1) {
      az[0] += __shfl_xor(az[0], m, 64);
      az[1] += __shfl_xor(az[1], m, 64);
      ar[0] += __shfl_xor(ar[0], m, 64);
      ar[1] += __shfl_xor(ar[1], m, 64);
    }
    if (lane == 0) {
      float rh[2];
      #pragma unroll
      for (int rr = 0; rr < 2; ++rr) {
        hprev[rr] = h_lds[rowA + rr];
        zv[rr]    = 1.f / (1.f + __expf(-(xzv[rr] + az[rr])));
        float rg  = 1.f / (1.f + __expf(-(xrv[rr] + ar[rr])));
        rh[rr]    = rg * hprev[rr];
      }
      publish2(rhcell + (t & 1) * HID, rowA, rh[0], rh[1], (unsigned)t);
    }

    // ---- exchange 2: (r*h)_t (tag t, parity t&1) ----
    {
      float2 rv = poll_pair(rhcell + (t & 1) * HID, tid, (unsigned)t, &budget);
      *(float2*)&rh_lds[2 * tid] = rv;
    }
    __syncthreads();                                   // [B2]

    float rr16[16];
    #pragma unroll
    for (int q = 0; q < 4; ++q)
      *(float4*)&rr16[q*4] = *(const float4*)&rh_lds[q * 256 + lane * 4];
    float ac[2] = {0.f, 0.f};
    #pragma unroll
    for (int rr = 0; rr < 2; ++rr)
      #pragma unroll
      for (int c = 0; c < 16; ++c)
        ac[rr] = fmaf(wgt[2][rr][c], rr16[c], ac[rr]);
    #pragma unroll
    for (int m = 1; m < 64; m <<= 1) {
      ac[0] += __shfl_xor(ac[0], m, 64);
      ac[1] += __shfl_xor(ac[1], m, 64);
    }
    if (lane == 0) {
      float hn[2];
      #pragma unroll
      for (int rr = 0; rr < 2; ++rr) {
        float cand = tanhf(xhv[rr] + ac[rr]);
        hn[rr]     = zv[rr] * hprev[rr] + (1.f - zv[rr]) * cand;
      }
      publish2(hcell + (t & 1) * HID, rowA, hn[0], hn[1], (unsigned)t);
      if (t == SEQLEN) { out[rowA] = hn[0]; out[rowA + 1] = hn[1]; }
    }
  }
}

// ---------------------------------------------------------------------------
extern "C" void kernel_launch(void* const* d_in, const int* in_sizes, int n_in,
                              void* d_out, int out_size, void* d_ws, size_t ws_size,
                              hipStream_t stream) {
  (void)in_sizes; (void)n_in; (void)out_size; (void)ws_size;

  const int*   seq = (const int*)d_in[0];
  const float* emb = (const float*)d_in[1];
  const float* Wrx = (const float*)d_in[2];
  const float* Wrh = (const float*)d_in[3];
  const float* Wzx = (const float*)d_in[4];
  const float* Wzh = (const float*)d_in[5];
  const float* Wx  = (const float*)d_in[6];
  const float* Wh  = (const float*)d_in[7];

  char* ws = (char*)d_ws;
  const size_t PROJ = (size_t)SEQLEN * HID * sizeof(float);   // 16 MB each
  float* xrT    = (float*)(ws);
  float* xzT    = (float*)(ws + PROJ);
  float* xhT    = (float*)(ws + 2 * PROJ);
  u64*   hcell  = (u64*)(ws + 3 * PROJ);                      // [2][HID]
  u64*   rhcell = hcell + 2 * HID;                            // [2][HID]

  // Tag reset every launch: 0xFFFFFFFF never matches a wanted tag in [1,4096].
  (void)hipMemsetAsync(hcell, 0xFF, 4 * HID * sizeof(u64), stream);

  proj_gemm<<<dim3(HID / 64, SEQLEN / 64, 3), 256, 0, stream>>>(
      seq, emb, Wrx, Wzx, Wx, xrT, xzT, xhT);

  rnn_scan<<<dim3(NWG), BLOCK, 0, stream>>>(
      Wzh, Wrh, Wh, xzT, xrT, xhT, hcell, rhcell, (float*)d_out);
}

// Round 9
// 25414.067 us; speedup vs baseline: 1.2296x; 1.1687x over previous
//
#include <hip/hip_runtime.h>
#include <stdint.h>

// GRU encoder: VOCAB=50257, EMBED=HIDDEN=1024, SEQ=4096.
// Phase 1: x-projections, output transposed [row][t].
// Phase 2: 4096-step scan, 64 scan-WGs x 512 threads (fused tag|value cells,
//          asm sc0sc1 polls, RMW publish = best measured protocol, R6) plus
//          ROUND-9 TREATMENT: 192 clock-warmer WGs (pure FMA, exit on a
//          dedicated done cell) + filler FMAs in the poll loop. Tests the
//          hypothesis that the persistent ~6us/step (and x1.5/x2/x2.4 replay
//          outliers) is DVFS downclocking of a 94%-idle GPU, not protocol.

#define HID    1024
#define SEQLEN 4096
#define NWG    64      // scan workgroups
#define NWG_T  256     // total grid incl. warmers (1 per CU)
#define RPW    16      // hidden rows per scan WG
#define BLOCK  512     // 8 waves; wave w owns rows 16g+2w, 16g+2w+1

typedef unsigned long long u64;

// ---------------------------------------------------------------------------
// Phase 1: CT[i][t] = sum_e emb[seq[t],e] * W[i,e]   (transposed output)
// ---------------------------------------------------------------------------
__global__ __launch_bounds__(256) void proj_gemm(
    const int* __restrict__ seq, const float* __restrict__ emb,
    const float* __restrict__ Wrx, const float* __restrict__ Wzx,
    const float* __restrict__ Wx,
    float* __restrict__ xrT, float* __restrict__ xzT, float* __restrict__ xhT)
{
  __shared__ float As[32][68];   // [k][t]
  __shared__ float Bs[32][68];   // [k][i]
  __shared__ int   idx[64];

  const float* W = (blockIdx.z == 0) ? Wrx : (blockIdx.z == 1) ? Wzx : Wx;
  float*       C = (blockIdx.z == 0) ? xrT : (blockIdx.z == 1) ? xzT : xhT;

  const int tid = threadIdx.x;
  const int t0 = blockIdx.y * 64;
  const int i0 = blockIdx.x * 64;
  if (tid < 64) idx[tid] = seq[t0 + tid];
  __syncthreads();

  float acc[4][4] = {};                     // acc[i][j]: i-dim x t-dim
  const int tx = tid & 15, ty = tid >> 4;
  const int c4 = (tid & 7) * 4;
  const int r8 = tid >> 3;

  for (int k0 = 0; k0 < HID; k0 += 32) {
    for (int l = 0; l < 2; ++l) {
      const int rr = r8 + l * 32;
      float4 av = *(const float4*)(emb + (size_t)idx[rr] * HID + k0 + c4);
      As[c4+0][rr]=av.x; As[c4+1][rr]=av.y; As[c4+2][rr]=av.z; As[c4+3][rr]=av.w;
      float4 bv = *(const float4*)(W + (size_t)(i0 + rr) * HID + k0 + c4);
      Bs[c4+0][rr]=bv.x; Bs[c4+1][rr]=bv.y; Bs[c4+2][rr]=bv.z; Bs[c4+3][rr]=bv.w;
    }
    __syncthreads();
    #pragma unroll
    for (int k = 0; k < 32; ++k) {
      float a[4], b[4];
      *(float4*)a = *(const float4*)&Bs[k][ty * 4];   // i-dim (rows of CT)
      *(float4*)b = *(const float4*)&As[k][tx * 4];   // t-dim (cols of CT)
      #pragma unroll
      for (int i = 0; i < 4; ++i)
        #pragma unroll
        for (int j = 0; j < 4; ++j)
          acc[i][j] = fmaf(a[i], b[j], acc[i][j]);
    }
    __syncthreads();
  }
  #pragma unroll
  for (int i = 0; i < 4; ++i) {
    float4 v = make_float4(acc[i][0], acc[i][1], acc[i][2], acc[i][3]);
    *(float4*)(C + (size_t)(i0 + ty * 4 + i) * SEQLEN + t0 + tx * 4) = v;
  }
}

// ---------------------------------------------------------------------------
// Fused-cell primitives. Cell = u64 {low: f32 bits, high: step tag}.
// ---------------------------------------------------------------------------
__device__ __forceinline__ void publish2(u64* cells, int row, float a, float b,
                                         unsigned tag) {
  u64 ca = ((u64)tag << 32) | (u64)__float_as_uint(a);
  u64 cb = ((u64)tag << 32) | (u64)__float_as_uint(b);
  (void)__hip_atomic_exchange(&cells[row],     ca, __ATOMIC_RELAXED,
                              __HIP_MEMORY_SCOPE_AGENT);
  (void)__hip_atomic_exchange(&cells[row + 1], cb, __ATOMIC_RELAXED,
                              __HIP_MEMORY_SCOPE_AGENT);
}

// Poll this thread's 16B cell-pair until both tags == want, with independent
// FMA filler chains each round (keeps the CU's VALU measurably busy during
// the vmcnt stall -> DVFS signal). Load+waitcnt stay in ONE asm block (the
// R2/rule-18-safe pattern). Budget bail-out avoids hangs.
__device__ __forceinline__ float2 poll_pair(const u64* cells, int pair,
                                            unsigned want, int* budget,
                                            float* warm) {
  const float* p = (const float*)(cells + 2 * pair);
  float4 v;
  float w0 = *warm, w1 = w0 + 0.1f, w2 = w0 + 0.2f, w3 = w0 + 0.3f;
  for (;;) {
    #pragma unroll
    for (int i = 0; i < 12; ++i) {          // 48 independent FMAs (~40 ns)
      w0 = fmaf(w0, 0.9999f, 1e-4f); w1 = fmaf(w1, 0.9998f, 1e-4f);
      w2 = fmaf(w2, 0.9997f, 1e-4f); w3 = fmaf(w3, 0.9996f, 1e-4f);
    }
    asm volatile("global_load_dwordx4 %0, %1, off sc0 sc1\n\ts_waitcnt vmcnt(0)"
                 : "=v"(v) : "v"(p) : "memory");
    if (__float_as_uint(v.y) == want && __float_as_uint(v.w) == want) break;
    if (--(*budget) <= 0) break;
  }
  *warm = w0 + w1 + w2 + w3;
  return make_float2(v.x, v.z);
}

// ---------------------------------------------------------------------------
// Phase 2. Blocks [0,64): persistent scan, identical protocol to R6 (+R7
// transposed x). Blocks [64,256): clock warmers -- pure FMA chains, checking
// a dedicated `done` cell every ~2.6us, exiting when the scan finishes.
// ---------------------------------------------------------------------------
__global__ __launch_bounds__(BLOCK, 2) void rnn_scan(
    const float* __restrict__ Wzh, const float* __restrict__ Wrh,
    const float* __restrict__ Whh,
    const float* __restrict__ xzT, const float* __restrict__ xrT,
    const float* __restrict__ xhT,
    u64* __restrict__ hcell,     // [2][HID]
    u64* __restrict__ rhcell,    // [2][HID]
    u64* __restrict__ done,      // [1] scan-finished doorbell
    float* __restrict__ out)
{
  const int tid  = threadIdx.x;
  const int g    = blockIdx.x;

  if (g >= NWG) {
    // ---- clock warmer: keep SCLK/FCLK pinned while the scan runs ----
    float a0 = 1.0f + tid * 1e-6f, a1 = 1.1f, a2 = 1.2f,
          a3 = 1.3f, a4 = 1.4f, a5 = 1.5f;
    int wb = 1 << 16;                        // ~220 ms cap, no-hang guarantee
    for (;;) {
      #pragma unroll 4
      for (int i = 0; i < 512; ++i) {        // ~3072 FMAs ≈ 2.6 us
        a0 = fmaf(a0, 0.9999f, 1e-4f); a1 = fmaf(a1, 0.9998f, 1e-4f);
        a2 = fmaf(a2, 0.9997f, 1e-4f); a3 = fmaf(a3, 0.9996f, 1e-4f);
        a4 = fmaf(a4, 0.9995f, 1e-4f); a5 = fmaf(a5, 0.9994f, 1e-4f);
      }
      asm volatile("" :: "v"(a0), "v"(a1), "v"(a2), "v"(a3), "v"(a4), "v"(a5));
      u64 d = __hip_atomic_load((u64*)done, __ATOMIC_RELAXED,
                                __HIP_MEMORY_SCOPE_AGENT);
      if (d != 0) break;
      if (--wb <= 0) break;
    }
    return;
  }

  const int wave = tid >> 6, lane = tid & 63;
  const int rowA = g * RPW + wave * 2;

  __shared__ float h_lds[HID];
  __shared__ float rh_lds[HID];

  // Weights: wgt[m][rr][q*4+j] = Wm[rowA+rr][q*256 + 4*lane + j].
  float wgt[3][2][16];
  #pragma unroll
  for (int m = 0; m < 3; ++m) {
    const float* Wm = (m == 0) ? Wzh : (m == 1) ? Wrh : Whh;
    #pragma unroll
    for (int rr = 0; rr < 2; ++rr) {
      const float* p = Wm + (size_t)(rowA + rr) * HID + lane * 4;
      #pragma unroll
      for (int q = 0; q < 4; ++q) {
        float4 v = *(const float4*)(p + q * 256);
        wgt[m][rr][q*4+0] = v.x; wgt[m][rr][q*4+1] = v.y;
        wgt[m][rr][q*4+2] = v.z; wgt[m][rr][q*4+3] = v.w;
      }
    }
  }

  int budget = 1 << 21;
  float warm = 0.5f + lane * 1e-3f;
  float xzv[2], xrv[2], xhv[2], zv[2], hprev[2];

  for (int t = 1; t <= SEQLEN; ++t) {
    // ---- exchange 1: h_{t-1} (tag t-1, parity (t-1)&1) ----
    if (t == 1) {
      *(float2*)&h_lds[2 * tid] = make_float2(0.f, 0.f);
    } else {
      float2 hv = poll_pair(hcell + ((t - 1) & 1) * HID, tid,
                            (unsigned)(t - 1), &budget, &warm);
      *(float2*)&h_lds[2 * tid] = hv;
    }

    // x rows ([row][t] layout -> L1-hot): hides under B1.
    if (lane == 0) {
      #pragma unroll
      for (int rr = 0; rr < 2; ++rr) {
        xzv[rr] = xzT[(size_t)(rowA + rr) * SEQLEN + (t - 1)];
        xrv[rr] = xrT[(size_t)(rowA + rr) * SEQLEN + (t - 1)];
        xhv[rr] = xhT[(size_t)(rowA + rr) * SEQLEN + (t - 1)];
      }
    }
    __syncthreads();                                   // [B1]

    // gate dots over q-strided 16 columns, 64-lane shuffle reduce.
    float hr[16];
    #pragma unroll
    for (int q = 0; q < 4; ++q)
      *(float4*)&hr[q*4] = *(const float4*)&h_lds[q * 256 + lane * 4];
    float az[2] = {0.f, 0.f}, ar[2] = {0.f, 0.f};
    #pragma unroll
    for (int rr = 0; rr < 2; ++rr)
      #pragma unroll
      for (int c = 0; c < 16; ++c) {
        az[rr] = fmaf(wgt[0][rr][c], hr[c], az[rr]);
        ar[rr] = fmaf(wgt[1][rr][c], hr[c], ar[rr]);
      }
    #pragma unroll
    for (int m = 1; m < 64; m <<= 1) {
      az[0] += __shfl_xor(az[0], m, 64);
      az[1] += __shfl_xor(az[1], m, 64);
      ar[0] += __shfl_xor(ar[0], m, 64);
      ar[1] += __shfl_xor(ar[1], m, 64);
    }
    if (lane == 0) {
      float rh[2];
      #pragma unroll
      for (int rr = 0; rr < 2; ++rr) {
        hprev[rr] = h_lds[rowA + rr];
        zv[rr]    = 1.f / (1.f + __expf(-(xzv[rr] + az[rr])));
        float rg  = 1.f / (1.f + __expf(-(xrv[rr] + ar[rr])));
        rh[rr]    = rg * hprev[rr];
      }
      publish2(rhcell + (t & 1) * HID, rowA, rh[0], rh[1], (unsigned)t);
    }

    // ---- exchange 2: (r*h)_t (tag t, parity t&1) ----
    {
      float2 rv = poll_pair(rhcell + (t & 1) * HID, tid, (unsigned)t,
                            &budget, &warm);
      *(float2*)&rh_lds[2 * tid] = rv;
    }
    __syncthreads();                                   // [B2]

    float rr16[16];
    #pragma unroll
    for (int q = 0; q < 4; ++q)
      *(float4*)&rr16[q*4] = *(const float4*)&rh_lds[q * 256 + lane * 4];
    float ac[2] = {0.f, 0.f};
    #pragma unroll
    for (int rr = 0; rr < 2; ++rr)
      #pragma unroll
      for (int c = 0; c < 16; ++c)
        ac[rr] = fmaf(wgt[2][rr][c], rr16[c], ac[rr]);
    #pragma unroll
    for (int m = 1; m < 64; m <<= 1) {
      ac[0] += __shfl_xor(ac[0], m, 64);
      ac[1] += __shfl_xor(ac[1], m, 64);
    }
    if (lane == 0) {
      float hn[2];
      #pragma unroll
      for (int rr = 0; rr < 2; ++rr) {
        float cand = tanhf(xhv[rr] + ac[rr]);
        hn[rr]     = zv[rr] * hprev[rr] + (1.f - zv[rr]) * cand;
      }
      publish2(hcell + (t & 1) * HID, rowA, hn[0], hn[1], (unsigned)t);
      if (t == SEQLEN) { out[rowA] = hn[0]; out[rowA + 1] = hn[1]; }
    }
  }

  asm volatile("" :: "v"(warm));              // keep filler chains live
  if (g == 0 && tid == 0)                     // release the warmers
    (void)__hip_atomic_exchange(done, 1ull, __ATOMIC_RELAXED,
                                __HIP_MEMORY_SCOPE_AGENT);
}

// ---------------------------------------------------------------------------
extern "C" void kernel_launch(void* const* d_in, const int* in_sizes, int n_in,
                              void* d_out, int out_size, void* d_ws, size_t ws_size,
                              hipStream_t stream) {
  (void)in_sizes; (void)n_in; (void)out_size; (void)ws_size;

  const int*   seq = (const int*)d_in[0];
  const float* emb = (const float*)d_in[1];
  const float* Wrx = (const float*)d_in[2];
  const float* Wrh = (const float*)d_in[3];
  const float* Wzx = (const float*)d_in[4];
  const float* Wzh = (const float*)d_in[5];
  const float* Wx  = (const float*)d_in[6];
  const float* Wh  = (const float*)d_in[7];

  char* ws = (char*)d_ws;
  const size_t PROJ = (size_t)SEQLEN * HID * sizeof(float);   // 16 MB each
  float* xrT    = (float*)(ws);
  float* xzT    = (float*)(ws + PROJ);
  float* xhT    = (float*)(ws + 2 * PROJ);
  u64*   hcell  = (u64*)(ws + 3 * PROJ);                      // [2][HID]
  u64*   rhcell = hcell + 2 * HID;                            // [2][HID]
  u64*   done   = rhcell + 2 * HID;                           // [1]

  // Per-launch reset (replay-safe): tags to 0xFF (never matches 1..4096),
  // done doorbell to 0.
  (void)hipMemsetAsync(hcell, 0xFF, 4 * HID * sizeof(u64), stream);
  (void)hipMemsetAsync(done, 0x00, sizeof(u64), stream);

  proj_gemm<<<dim3(HID / 64, SEQLEN / 64, 3), 256, 0, stream>>>(
      seq, emb, Wrx, Wzx, Wx, xrT, xzT, xhT);

  rnn_scan<<<dim3(NWG_T), BLOCK, 0, stream>>>(
      Wzh, Wrh, Wh, xzT, xrT, xhT, hcell, rhcell, done, (float*)d_out);
}